// Round 5
// baseline (265.496 us; speedup 1.0000x reference)
//
#include <hip/hip_runtime.h>

// ExpandEvecs: out[b][k][n][m] = sum_{j<=k} e[b][n][j] * e[b][m][j]
// B=4, C=1, N=1024, K=16. fp32 in / fp32 out. Output 268.4 MB.
// dur_us = harness re-poison fill (~162 us, always the top-5 rows) + kernel.
// Kernel times: R4 ~94, R5 ~170, R6 ~102, R7 ~96 us vs ~41 us fill-rate floor.
//
// R8/R9 (nontemporal stores). R4/R6/R7 tried: fenced vs unfenced stores,
// 512/4096/8192 blocks, plane-scattered vs linear global write sweep,
// gathered vs coalesced loads -- ALL land at ~2.8 TB/s write stream while
// the rocclr fill does 6.6 TB/s into the same buffer. Store pattern, store
// fencing, and loads are falsified as the limiter. Remaining suspect: the
// 268 MB write-once stream goes through L2/L3 write-allocate; footprint >
// L3 (256 MB) => every store allocates+evicts a dirty line (double
// handling). Fix: __builtin_nontemporal_store (nt flag) on the output
// burst -- stream past cache allocation. Single-variable A/B vs R7.
// R9: compile fix -- the builtin needs a clang ext_vector_type, not HIP's
// float4 class.

#define BB 4
#define NN 1024
#define KK 16
#define ROWS 8
#define NCHUNK (NN / ROWS)   // 128 n-chunks per (b,k) plane

typedef float f32x4 __attribute__((ext_vector_type(4)));

__device__ __forceinline__ void nt_store4(float* p, float a, float b,
                                          float c, float d) {
    f32x4 v; v.x = a; v.y = b; v.z = c; v.w = d;
    __builtin_nontemporal_store(v, (f32x4*)p);
}

__global__ __launch_bounds__(256) void ExpandEvecs_75780402970966_evT(
    const float* __restrict__ ev,   // [B][N][K]
    float* __restrict__ evT)        // [B][K][N]
{
    const int b  = blockIdx.x >> 2;
    const int mc = blockIdx.x & 3;
    const int m  = mc * 256 + threadIdx.x;
    const float* src = ev + (size_t)(b * NN + m) * KK;
    float* dst = evT + (size_t)b * KK * NN + m;
#pragma unroll
    for (int k = 0; k < KK; ++k)
        dst[(size_t)k * NN] = src[k];   // coalesced stores, tiny gather reads
}

__global__ __launch_bounds__(256) void ExpandEvecs_75780402970966_kernel(
    const float* __restrict__ ev,   // [B][N][K] float32 (for uniform n-rows)
    const float* __restrict__ evT,  // [B][K][N] float32 (workspace)
    float* __restrict__ out)        // [B][K][N][N] float32
{
    const int tid = threadIdx.x;
    const int m0  = tid << 2;                 // 256 threads x 4 m = all 1024 m
    const unsigned bid = blockIdx.x;
    const int grp = bid & (NCHUNK - 1);       // fastest: linear sweep within
    const int bk  = bid >> 7;                 //   a (b,k) plane
    const int k   = bk & (KK - 1);
    const int b   = bk >> 4;
    const int n0  = grp * ROWS;

    const float* __restrict__ eb = ev + (size_t)b * NN * KK;
    const float* __restrict__ eT = evT + (size_t)b * KK * NN + m0;

    float acc[ROWS][4];
#pragma unroll
    for (int r = 0; r < ROWS; ++r)
#pragma unroll
        for (int v = 0; v < 4; ++v) acc[r][v] = 0.0f;

#pragma unroll
    for (int kb = 0; kb < KK / 4; ++kb) {      // j in blocks of 4
        if (kb * 4 <= k) {                     // block-uniform: skip dead work
            float4 em4[4];                     // em4[jj] = evT[j][m0..m0+3]
#pragma unroll
            for (int jj = 0; jj < 4; ++jj)
                em4[jj] = *(const float4*)(eT + (size_t)(kb * 4 + jj) * NN);

            float4 en4[ROWS];                  // block-uniform -> s_load_x4
#pragma unroll
            for (int r = 0; r < ROWS; ++r)
                en4[r] = *(const float4*)(eb + (size_t)(n0 + r) * KK + kb * 4);

#pragma unroll
            for (int jj = 0; jj < 4; ++jj) {
                const int j = kb * 4 + jj;
                if (j <= k) {                  // block-uniform guard
#pragma unroll
                    for (int r = 0; r < ROWS; ++r) {
                        const float enk = ((const float*)&en4[r])[jj];
#pragma unroll
                        for (int v = 0; v < 4; ++v)
                            acc[r][v] = fmaf(((const float*)&em4[jj])[v], enk,
                                             acc[r][v]);
                    }
                }
            }
        }
    }

    // Epilogue: 8 contiguous 16B NONTEMPORAL stores = 32 KiB/block,
    // consecutive blocks -> consecutive 32 KiB. Write-once data: stream
    // past L2/L3 allocation (nt), never waited on.
    const size_t kplane = (size_t)NN * NN;
    float* ob = out + ((size_t)(b * KK + k)) * kplane
                    + (size_t)n0 * NN + (size_t)m0;
#pragma unroll
    for (int r = 0; r < ROWS; ++r)
        nt_store4(ob + (size_t)r * NN,
                  acc[r][0], acc[r][1], acc[r][2], acc[r][3]);
}

// Fallback (no workspace): one block per (b,n) row, reads ev directly with
// in-register component select. Correctness only.
__global__ __launch_bounds__(256) void ExpandEvecs_75780402970966_fallback(
    const float* __restrict__ ev, float* __restrict__ out)
{
    const int tid = threadIdx.x;
    const int m0  = tid << 2;
    const int n   = blockIdx.x & (NN - 1);
    const int b   = blockIdx.x >> 10;
    const float* __restrict__ en = ev + (size_t)(b * NN + n) * KK;

    float4 f[16];
    const float* base = ev + ((size_t)b * NN + m0) * KK;
#pragma unroll
    for (int i = 0; i < 16; ++i)
        f[i] = *(const float4*)(base + i * 4);

    float4 v[KK];
#pragma unroll
    for (int k = 0; k < KK; ++k) {
        float4 t;
        t.x = ((const float*)&f[0  + (k >> 2)])[k & 3];
        t.y = ((const float*)&f[4  + (k >> 2)])[k & 3];
        t.z = ((const float*)&f[8  + (k >> 2)])[k & 3];
        t.w = ((const float*)&f[12 + (k >> 2)])[k & 3];
        v[k] = t;
    }
    {
        const float e0 = en[0];
        v[0].x *= e0; v[0].y *= e0; v[0].z *= e0; v[0].w *= e0;
    }
#pragma unroll
    for (int k = 1; k < KK; ++k) {
        const float ek = en[k];
        v[k].x = fmaf(v[k].x, ek, v[k - 1].x);
        v[k].y = fmaf(v[k].y, ek, v[k - 1].y);
        v[k].z = fmaf(v[k].z, ek, v[k - 1].z);
        v[k].w = fmaf(v[k].w, ek, v[k - 1].w);
    }
    const size_t kplane = (size_t)NN * NN;
    float* ob = out + (size_t)b * KK * kplane + (size_t)n * NN + m0;
#pragma unroll
    for (int k = 0; k < KK; ++k)
        nt_store4(ob + (size_t)k * kplane, v[k].x, v[k].y, v[k].z, v[k].w);
}

extern "C" void kernel_launch(void* const* d_in, const int* in_sizes, int n_in,
                              void* d_out, int out_size, void* d_ws, size_t ws_size,
                              hipStream_t stream) {
    const float* ev = (const float*)d_in[0];
    float* out = (float*)d_out;

    const size_t evT_bytes = (size_t)BB * KK * NN * sizeof(float);  // 256 KB
    if (ws_size >= evT_bytes && d_ws != nullptr) {
        float* evT = (float*)d_ws;
        ExpandEvecs_75780402970966_evT<<<BB * 4, 256, 0, stream>>>(ev, evT);
        ExpandEvecs_75780402970966_kernel
            <<<BB * KK * NCHUNK, 256, 0, stream>>>(ev, evT, out);
    } else {
        ExpandEvecs_75780402970966_fallback
            <<<BB * NN, 256, 0, stream>>>(ev, out);
    }
}